// Round 6
// baseline (314.946 us; speedup 1.0000x reference)
//
#include <hip/hip_runtime.h>

#define TOPK 500
#define NCLS 80
#define NPOS 196   // 14*14
#define NLEV 5
#define OUT_B_OFF 0
#define OUT_C_OFF 2000
#define OUT_R_OFF 42000

typedef float nfloat4 __attribute__((ext_vector_type(4)));

// ---------------- workspace layout (bytes) ----------------
#define WS_STATE   0        // int[16]: 5=nGt 6=nEq
#define WS_BAR     64       // int[16]: grid barrier counters
#define WS_HIST    128      // int[4][256]
#define WS_GT      8192     // int[512]
#define WS_EQ      12288    // int[1024]
#define WS_TOP     16384    // int[512]
#define WS_BOXP    20480    // float4[512]
#define WS_SCORES  40960    // float[N]
#define WS_BF16    (1u << 20)
#define FEAT_PX    21824    // 16384+4096+1024+256+64
#define BF16_BYTES ((size_t)FEAT_PX * 256 * 2)

#define TOPK_BLOCKS 256

__device__ inline unsigned short f2bf(float f) {
    unsigned u = __float_as_uint(f);
    return (unsigned short)((u + 0x7FFFu + ((u >> 16) & 1u)) >> 16);
}

// fused: blocks [0,SC) scores (block 0 also zeroes control ws); [SC,..) feats->bf16
#define SC_BLOCKS 768
__global__ __launch_bounds__(256) void k_prep(
    const float* __restrict__ cls, float* __restrict__ scores, int* __restrict__ ctrl, int N,
    const float* __restrict__ p3, const float* __restrict__ p4,
    const float* __restrict__ p5, const float* __restrict__ p6,
    const float* __restrict__ p7, ushort* __restrict__ dst) {
    int b = blockIdx.x;
    int t = threadIdx.x;
    if (b < SC_BLOCKS) {
        if (b == 0) {   // zero state+bar+hist: (128 + 4096)/4 = 1056 ints
            for (int z = t; z < 1056; z += 256) ctrl[z] = 0;
        }
        int i = b * 256 + t;
        if (i < N) {
            const float4* p = (const float4*)(cls + (size_t)i * NCLS);
            float m = -1e30f;
#pragma unroll
            for (int k = 0; k < NCLS / 4; ++k) {
                float4 v = p[k];
                m = fmaxf(m, fmaxf(fmaxf(v.x, v.y), fmaxf(v.z, v.w)));
            }
            scores[i] = m;
        }
    } else {
        int i = (b - SC_BLOCKS) * 256 + t;  // float4 chunk, total 1,396,736
        const int n0 = 1048576, n1 = 262144, n2 = 65536, n3 = 16384;
        const float* src; int off;
        if (i < n0)               { src = p3; off = i; }
        else if (i < n0+n1)       { src = p4; off = i - n0; }
        else if (i < n0+n1+n2)    { src = p5; off = i - n0 - n1; }
        else if (i < n0+n1+n2+n3) { src = p6; off = i - n0 - n1 - n2; }
        else                      { src = p7; off = i - n0 - n1 - n2 - n3; }
        float4 v = ((const float4*)src)[off];
        ushort4 r;
        r.x = f2bf(v.x); r.y = f2bf(v.y); r.z = f2bf(v.z); r.w = f2bf(v.w);
        ((ushort4*)dst)[i] = r;
    }
}

// persistent fused top-k: 4 radix passes + collect + rank + gather.
// 256 co-resident blocks; grid barriers via device atomics (fresh counter per barrier).
__global__ __launch_bounds__(256) void k_topk(
    const float* __restrict__ scores, int N,
    int* hist, int* state, int* bar, int* gtIdx, int* eqIdx,
    const float* __restrict__ boxes, const float* __restrict__ cls,
    const int* __restrict__ ishape,
    int* __restrict__ topIdx, float* __restrict__ boxp, float* __restrict__ out) {
    __shared__ int ss[256];
    __shared__ int lh[256];
    __shared__ int sCh, sK;
    __shared__ unsigned long long key[1024];
    __shared__ int ordTop[TOPK];
    int t = threadIdx.x;
    int gsz = gridDim.x * 256;
    unsigned prefix = 0;
    int k = TOPK;

    for (int p = 0; p < 4; ++p) {
        int shift = 24 - 8 * p;
        unsigned mask = (p == 0) ? 0u : (0xFFFFFFFFu << (32 - 8 * p));
        lh[t] = 0;
        __syncthreads();
        for (int i = blockIdx.x * 256 + t; i < N; i += gsz) {
            unsigned bits = __float_as_uint(scores[i]);
            if ((bits & mask) == prefix)
                atomicAdd(&lh[(bits >> shift) & 0xFF], 1);
        }
        __syncthreads();
        { int c = lh[t]; if (c) atomicAdd(&hist[(p << 8) + t], c); }
        // ---- grid barrier p ----
        __threadfence();
        __syncthreads();
        if (t == 0) {
            atomicAdd(&bar[p], 1);
            while (atomicAdd(&bar[p], 0) < TOPK_BLOCKS) __builtin_amdgcn_s_sleep(8);
            __threadfence();
        }
        __syncthreads();
        // ---- parallel replay of row p: suffix-sum + pick ----
        ss[t] = atomicAdd(&hist[(p << 8) + t], 0);
        __syncthreads();
        for (int o = 1; o < 256; o <<= 1) {
            int v = (t + o < 256) ? ss[t + o] : 0;
            __syncthreads();
            ss[t] += v;
            __syncthreads();
        }
        if (ss[t] >= k && (t == 255 || ss[t + 1] < k)) {
            sCh = t;
            sK = k - ((t == 255) ? 0 : ss[t + 1]);
        }
        __syncthreads();
        prefix |= ((unsigned)sCh) << shift;
        k = sK;
        __syncthreads();
    }

    // ---- collect candidates ----
    unsigned T = prefix;
    for (int i = blockIdx.x * 256 + t; i < N; i += gsz) {
        unsigned bits = __float_as_uint(scores[i]);
        if (bits > T) {
            int p2 = atomicAdd(&state[5], 1);
            if (p2 < 512) atomicExch(&gtIdx[p2], i);
        } else if (bits == T) {
            int p2 = atomicAdd(&state[6], 1);
            if (p2 < 1024) atomicExch(&eqIdx[p2], i);
        }
    }
    // ---- grid barrier 4 ----
    __threadfence();
    __syncthreads();
    if (t == 0) {
        atomicAdd(&bar[4], 1);
        while (atomicAdd(&bar[4], 0) < TOPK_BLOCKS) __builtin_amdgcn_s_sleep(8);
        __threadfence();
    }
    __syncthreads();
    if (blockIdx.x != 0) return;

    // ---- block 0: rank by counting, write topIdx/boxp, gather boxes+classes ----
    int cntGt  = min(atomicAdd(&state[5], 0), 512);
    int nEq    = atomicAdd(&state[6], 0);
    int eqTake = min(min(nEq, 1024), 1024 - cntGt);
    int total  = cntGt + eqTake;
    for (int q = t; q < 1024; q += 256) {
        unsigned long long kk = 0ull;
        if (q < cntGt) {
            int idx = atomicAdd(&gtIdx[q], 0);
            kk = ((unsigned long long)__float_as_uint(scores[idx]) << 32) | (unsigned)(~idx);
        } else if (q < total) {
            int idx = atomicAdd(&eqIdx[q - cntGt], 0);
            kk = ((unsigned long long)T << 32) | (unsigned)(~idx);
        }
        key[q] = kk;
    }
    __syncthreads();
    float hf = (float)ishape[1], wf = (float)ishape[2];
    for (int q = t; q < 1024; q += 256) {
        if (q < total) {
            unsigned long long me = key[q];
            int r = 0;
            for (int j2 = 0; j2 < 1024; ++j2) r += (key[j2] > me);
            if (r < TOPK) {
                int idx = (int)(~(unsigned)(me & 0xFFFFFFFFull));
                ordTop[r] = idx;
                topIdx[r] = idx;
                float bx1 = boxes[idx * 4 + 0], by1 = boxes[idx * 4 + 1];
                float bx2 = boxes[idx * 4 + 2], by2 = boxes[idx * 4 + 3];
                nfloat4 bp;
                bp.x = by1 / hf; bp.y = bx1 / wf;
                bp.z = (by2 - by1) / hf; bp.w = (bx2 - bx1) / wf;
                *(nfloat4*)(boxp + 4 * r) = bp;
            }
        }
    }
    __syncthreads();
    for (int e = t; e < TOPK * (NCLS + 4); e += 256) {
        int j2 = e / (NCLS + 4);
        int k2 = e - j2 * (NCLS + 4);
        int idx = ordTop[j2];
        if (k2 < 4) out[OUT_B_OFF + j2 * 4 + k2] = boxes[(size_t)idx * 4 + k2];
        else        out[OUT_C_OFF + j2 * NCLS + (k2 - 4)] = cls[(size_t)idx * NCLS + (k2 - 4)];
    }
}

// ROI: 4 positions / 256-thread block; 64 lanes/position, 4 channels/lane. bf16 feats.
template <int USE_BF16>
__global__ __launch_bounds__(256) void k_roi(
    const float* __restrict__ boxp, const int* __restrict__ topIdx,
    const ushort* __restrict__ feat,
    const float* __restrict__ f0, const float* __restrict__ f1,
    const float* __restrict__ f2, const float* __restrict__ f3,
    const float* __restrict__ f4,
    float* __restrict__ out) {
    const int lvlOff[5] = {0, 16384, 20480, 21504, 21760};
    // bijective XCD-chunked swizzle (m204)
    int nwg = gridDim.x;
    int q = nwg >> 3, r = nwg & 7;
    int orig = blockIdx.x;
    int xcd = orig & 7, i8 = orig >> 3;
    int wg = (xcd < r ? xcd * (q + 1) : r * (q + 1) + (xcd - r) * q) + i8;
    int P  = wg * 4 + (threadIdx.x >> 6);
    int c4 = threadIdx.x & 63;
    int j = P / NPOS;
    int pos = P - j * NPOS;
    int y = pos / 14, x = pos - (pos / 14) * 14;
    nfloat4 bp = *(const nfloat4*)(boxp + 4 * j);
    float ty = (float)y / 13.0f;
    float tx = (float)x / 13.0f;
    const float* fm[5] = {f0, f1, f2, f3, f4};
    float* o = out + OUT_R_OFF + (size_t)P * (NLEV * 256);
#pragma unroll
    for (int l = 0; l < NLEV; ++l) {
        int H = 128 >> l;
        float Hm1 = (float)(H - 1);
        float ys = (bp.x + ty * bp.z) * Hm1;
        float xs = (bp.y + tx * bp.w) * Hm1;
        float y0f = floorf(ys), x0f = floorf(xs);
        float wy = ys - y0f, wx = xs - x0f;
        int y0  = min(max((int)y0f, 0), H - 1);
        int y1c = min(max((int)y0f + 1, 0), H - 1);
        int x0  = min(max((int)x0f, 0), H - 1);
        int x1c = min(max((int)x0f + 1, 0), H - 1);
        bool valid = (ys >= 0.0f) && (ys <= Hm1) && (xs >= 0.0f) && (xs <= Hm1);
        float w00 = (1.0f - wy) * (1.0f - wx);
        float w01 = (1.0f - wy) * wx;
        float w10 = wy * (1.0f - wx);
        float w11 = wy * wx;
        nfloat4 res;
        if (USE_BF16) {
            const ushort* base = feat + ((size_t)lvlOff[l] << 8);
            ushort4 a = ((const ushort4*)(base + ((size_t)(y0  * H + x0 ) << 8)))[c4];
            ushort4 b = ((const ushort4*)(base + ((size_t)(y0  * H + x1c) << 8)))[c4];
            ushort4 c = ((const ushort4*)(base + ((size_t)(y1c * H + x0 ) << 8)))[c4];
            ushort4 d = ((const ushort4*)(base + ((size_t)(y1c * H + x1c) << 8)))[c4];
#define BF(u) __uint_as_float(((unsigned)(u)) << 16)
            res.x = w00 * BF(a.x) + w01 * BF(b.x) + w10 * BF(c.x) + w11 * BF(d.x);
            res.y = w00 * BF(a.y) + w01 * BF(b.y) + w10 * BF(c.y) + w11 * BF(d.y);
            res.z = w00 * BF(a.z) + w01 * BF(b.z) + w10 * BF(c.z) + w11 * BF(d.z);
            res.w = w00 * BF(a.w) + w01 * BF(b.w) + w10 * BF(c.w) + w11 * BF(d.w);
#undef BF
        } else {
            const float* f = fm[l];
            float4 a = ((const float4*)(f + ((size_t)(y0  * H + x0 ) << 8)))[c4];
            float4 b = ((const float4*)(f + ((size_t)(y0  * H + x1c) << 8)))[c4];
            float4 c = ((const float4*)(f + ((size_t)(y1c * H + x0 ) << 8)))[c4];
            float4 d = ((const float4*)(f + ((size_t)(y1c * H + x1c) << 8)))[c4];
            res.x = w00 * a.x + w01 * b.x + w10 * c.x + w11 * d.x;
            res.y = w00 * a.y + w01 * b.y + w10 * c.y + w11 * d.y;
            res.z = w00 * a.z + w01 * b.z + w10 * c.z + w11 * d.z;
            res.w = w00 * a.w + w01 * b.w + w10 * c.w + w11 * d.w;
        }
        if (!valid) { res.x = 0.f; res.y = 0.f; res.z = 0.f; res.w = 0.f; }
        __builtin_nontemporal_store(res, (nfloat4*)(o + l * 256) + c4);
    }
}

extern "C" void kernel_launch(void* const* d_in, const int* in_sizes, int n_in,
                              void* d_out, int out_size, void* d_ws, size_t ws_size,
                              hipStream_t stream) {
    const int*   ishape = (const int*)d_in[0];
    const float* boxes  = (const float*)d_in[1];
    const float* cls    = (const float*)d_in[2];
    const float* p3     = (const float*)d_in[3];
    const float* p4     = (const float*)d_in[4];
    const float* p5     = (const float*)d_in[5];
    const float* p6     = (const float*)d_in[6];
    const float* p7     = (const float*)d_in[7];
    float* out = (float*)d_out;

    int N = in_sizes[2] / NCLS;   // 196416

    char* ws = (char*)d_ws;
    int*    state  = (int*)(ws + WS_STATE);
    int*    bar    = (int*)(ws + WS_BAR);
    int*    hist   = (int*)(ws + WS_HIST);
    int*    gtIdx  = (int*)(ws + WS_GT);
    int*    eqIdx  = (int*)(ws + WS_EQ);
    int*    topIdx = (int*)(ws + WS_TOP);
    float*  boxp   = (float*)(ws + WS_BOXP);
    float*  scores = (float*)(ws + WS_SCORES);
    ushort* feat   = (ushort*)(ws + WS_BF16);

    bool useBf16 = ws_size >= (size_t)WS_BF16 + BF16_BYTES;

    hipLaunchKernelGGL(k_prep, dim3(useBf16 ? SC_BLOCKS + 5456 : SC_BLOCKS), dim3(256), 0, stream,
                       cls, scores, state, N, p3, p4, p5, p6, p7, feat);
    hipLaunchKernelGGL(k_topk, dim3(TOPK_BLOCKS), dim3(256), 0, stream,
                       scores, N, hist, state, bar, gtIdx, eqIdx,
                       boxes, cls, ishape, topIdx, boxp, out);
    if (useBf16)
        hipLaunchKernelGGL((k_roi<1>), dim3(TOPK * NPOS / 4), dim3(256), 0, stream,
                           boxp, topIdx, feat, p3, p4, p5, p6, p7, out);
    else
        hipLaunchKernelGGL((k_roi<0>), dim3(TOPK * NPOS / 4), dim3(256), 0, stream,
                           boxp, topIdx, feat, p3, p4, p5, p6, p7, out);
}

// Round 7
// 248.899 us; speedup vs baseline: 1.2654x; 1.2654x over previous
//
#include <hip/hip_runtime.h>

#define TOPK 500
#define NCLS 80
#define NPOS 196   // 14*14
#define NLEV 5
#define OUT_B_OFF 0
#define OUT_C_OFF 2000
#define OUT_R_OFF 42000

typedef float nfloat4 __attribute__((ext_vector_type(4)));

// ---------------- workspace layout (bytes) ----------------
#define WS_STATE   0          // int[16]: 5=nGt 6=nEq
#define WS_HIST    64         // int[4][256]
#define WS_GT      8192       // int[512]
#define WS_EQ      12288      // int[1024]
#define WS_TOP     16384      // int[512]
#define WS_BOXP    20480      // float4[512]
#define WS_SCORES  40960      // float[N] (~786 KB)
#define WS_FEAT    (1u << 20) // fp8 feats, 5.6 MB
#define FEAT_PX    21824      // 16384+4096+1024+256+64
#define FP8_BYTES  ((size_t)FEAT_PX * 256)

__global__ void k_init(int* state, int* hist) {
    int t = threadIdx.x;
    if (t < 1024) hist[t] = 0;
    if (t < 16) state[t] = 0;
}

// fused: blocks [0,SC) scores + pass-0 hist; blocks [SC,..) convert feats->fp8 (HW cvt)
#define SC_BLOCKS 768
__global__ __launch_bounds__(256) void k_prep(
    const float* __restrict__ cls, float* __restrict__ scores, int* __restrict__ hist, int N,
    const float* __restrict__ p3, const float* __restrict__ p4,
    const float* __restrict__ p5, const float* __restrict__ p6,
    const float* __restrict__ p7, unsigned* __restrict__ dst) {
    int b = blockIdx.x;
    int t = threadIdx.x;
    if (b < SC_BLOCKS) {
        __shared__ int lh[256];
        lh[t] = 0;
        __syncthreads();
        int i = b * 256 + t;
        if (i < N) {
            const float4* p = (const float4*)(cls + (size_t)i * NCLS);
            float m = -1e30f;
#pragma unroll
            for (int k = 0; k < NCLS / 4; ++k) {
                float4 v = p[k];
                m = fmaxf(m, fmaxf(fmaxf(v.x, v.y), fmaxf(v.z, v.w)));
            }
            scores[i] = m;
            atomicAdd(&lh[__float_as_uint(m) >> 24], 1);
        }
        __syncthreads();
        int c = lh[t];
        if (c) atomicAdd(&hist[t], c);
    } else {
        int i = (b - SC_BLOCKS) * 256 + t;  // float4 chunk, total 1,396,736
        const int n0 = 1048576, n1 = 262144, n2 = 65536, n3 = 16384;
        const float* src; int off;
        if (i < n0)               { src = p3; off = i; }
        else if (i < n0+n1)       { src = p4; off = i - n0; }
        else if (i < n0+n1+n2)    { src = p5; off = i - n0 - n1; }
        else if (i < n0+n1+n2+n3) { src = p6; off = i - n0 - n1 - n2; }
        else                      { src = p7; off = i - n0 - n1 - n2 - n3; }
        float4 v = ((const float4*)src)[off];
        int w8 = 0;
        w8 = __builtin_amdgcn_cvt_pk_fp8_f32(v.x, v.y, w8, false);
        w8 = __builtin_amdgcn_cvt_pk_fp8_f32(v.z, v.w, w8, true);
        dst[i] = (unsigned)w8;
    }
}

// replay radix picks from completed histograms (scores are positive floats)
__device__ inline unsigned replay_prefix(const int* hist, int passes) {
    int k = TOPK;
    unsigned prefix = 0;
    for (int p = 0; p < passes; ++p) {
        const int* h = hist + (p << 8);
        int cum = 0, chosen = 0;
        for (int b = 255; b >= 0; --b) {
            int hb = h[b];
            if (cum + hb >= k) { chosen = b; break; }
            cum += hb;
        }
        k -= cum;
        prefix |= ((unsigned)chosen) << (24 - 8 * p);
    }
    return prefix;
}

__global__ __launch_bounds__(256) void k_hist(
    const float* __restrict__ scores, int N,
    int* __restrict__ hist, int pass) {
    __shared__ int lh[256];
    __shared__ unsigned s_prefix;
    int t = threadIdx.x;
    lh[t] = 0;
    if (t == 0) s_prefix = replay_prefix(hist, pass);
    __syncthreads();
    unsigned prefix = s_prefix;
    int shift = 24 - 8 * pass;
    unsigned mask = 0xFFFFFFFFu << (32 - 8 * pass);
    for (int i = blockIdx.x * blockDim.x + t; i < N; i += gridDim.x * blockDim.x) {
        unsigned bits = __float_as_uint(scores[i]);
        if ((bits & mask) == prefix)
            atomicAdd(&lh[(bits >> shift) & 0xFF], 1);
    }
    __syncthreads();
    int c = lh[t];
    if (c) atomicAdd(&hist[pass * 256 + t], c);
}

__global__ __launch_bounds__(256) void k_collect(
    const float* __restrict__ scores, int N, const int* __restrict__ hist,
    int* state, int* gtIdx, int* eqIdx) {
    __shared__ unsigned sT;
    if (threadIdx.x == 0) sT = replay_prefix(hist, 4);
    __syncthreads();
    unsigned T = sT;
    int i = blockIdx.x * blockDim.x + threadIdx.x;
    if (i >= N) return;
    unsigned bits = __float_as_uint(scores[i]);
    if (bits > T) {
        int p = atomicAdd(&state[5], 1);
        if (p < 512) gtIdx[p] = i;
    } else if (bits == T) {
        int p = atomicAdd(&state[6], 1);
        if (p < 1024) eqIdx[p] = i;
    }
}

// single-block: rank by counting, write topIdx + boxp, gather boxes/classes into out.
__global__ __launch_bounds__(1024) void k_sel(
    const float* __restrict__ scores, const int* __restrict__ hist,
    const int* __restrict__ state,
    const int* __restrict__ gtIdx, const int* __restrict__ eqIdx,
    const float* __restrict__ boxes, const float* __restrict__ cls,
    const int* __restrict__ ishape,
    int* __restrict__ topIdx, float* __restrict__ boxp, float* __restrict__ out) {
    __shared__ unsigned long long key[1024];
    __shared__ int ordTop[TOPK];
    __shared__ unsigned sT;
    int tid = threadIdx.x;
    if (tid == 0) sT = replay_prefix(hist, 4);
    __syncthreads();
    unsigned T = sT;
    int cntGt  = min(state[5], 512);
    int eqTake = min(min(state[6], 1024), 1024 - cntGt);
    int total  = cntGt + eqTake;
    unsigned long long me = 0ull;
    int myIdx = -1;
    if (tid < cntGt) {
        myIdx = gtIdx[tid];
        me = ((unsigned long long)__float_as_uint(scores[myIdx]) << 32) | (unsigned)(~myIdx);
    } else if (tid < total) {
        myIdx = eqIdx[tid - cntGt];
        me = ((unsigned long long)T << 32) | (unsigned)(~myIdx);
    }
    key[tid] = me;
    __syncthreads();
    float hf = (float)ishape[1], wf = (float)ishape[2];
    if (tid < total) {
        int r = 0;
        for (int j = 0; j < 1024; ++j) r += (key[j] > me);
        if (r < TOPK) {
            topIdx[r] = myIdx;
            ordTop[r] = myIdx;
            float bx1 = boxes[myIdx * 4 + 0], by1 = boxes[myIdx * 4 + 1];
            float bx2 = boxes[myIdx * 4 + 2], by2 = boxes[myIdx * 4 + 3];
            nfloat4 bp;
            bp.x = by1 / hf; bp.y = bx1 / wf;
            bp.z = (by2 - by1) / hf; bp.w = (bx2 - bx1) / wf;
            *(nfloat4*)(boxp + 4 * r) = bp;
        }
    }
    __syncthreads();
    for (int e = tid; e < TOPK * (NCLS + 4); e += 1024) {
        int j = e / (NCLS + 4);
        int k = e - j * (NCLS + 4);
        int idx = ordTop[j];
        if (k < 4) out[OUT_B_OFF + j * 4 + k] = boxes[(size_t)idx * 4 + k];
        else       out[OUT_C_OFF + j * NCLS + (k - 4)] = cls[(size_t)idx * NCLS + (k - 4)];
    }
}

// ROI: 4 positions / 256-thread block; 64 lanes/position, 4 channels/lane.
// fp8 feats decoded with HW v_cvt_pk_f32_fp8.
template <int USE_FP8>
__global__ __launch_bounds__(256) void k_roi(
    const float* __restrict__ boxp, const int* __restrict__ topIdx,
    const unsigned char* __restrict__ feat,
    const float* __restrict__ f0, const float* __restrict__ f1,
    const float* __restrict__ f2, const float* __restrict__ f3,
    const float* __restrict__ f4,
    float* __restrict__ out) {
    const int lvlOff[5] = {0, 16384, 20480, 21504, 21760};
    // bijective XCD-chunked swizzle (m204)
    int nwg = gridDim.x;
    int q = nwg >> 3, r = nwg & 7;
    int orig = blockIdx.x;
    int xcd = orig & 7, i8 = orig >> 3;
    int wg = (xcd < r ? xcd * (q + 1) : r * (q + 1) + (xcd - r) * q) + i8;
    int P  = wg * 4 + (threadIdx.x >> 6);
    int c4 = threadIdx.x & 63;
    int j = P / NPOS;
    int pos = P - j * NPOS;
    int y = pos / 14, x = pos - (pos / 14) * 14;
    nfloat4 bp = *(const nfloat4*)(boxp + 4 * j);
    float ty = (float)y / 13.0f;
    float tx = (float)x / 13.0f;
    const float* fm[5] = {f0, f1, f2, f3, f4};
    float* o = out + OUT_R_OFF + (size_t)P * (NLEV * 256);
#pragma unroll
    for (int l = 0; l < NLEV; ++l) {
        int H = 128 >> l;
        float Hm1 = (float)(H - 1);
        float ys = (bp.x + ty * bp.z) * Hm1;
        float xs = (bp.y + tx * bp.w) * Hm1;
        float y0f = floorf(ys), x0f = floorf(xs);
        float wy = ys - y0f, wx = xs - x0f;
        int y0  = min(max((int)y0f, 0), H - 1);
        int y1c = min(max((int)y0f + 1, 0), H - 1);
        int x0  = min(max((int)x0f, 0), H - 1);
        int x1c = min(max((int)x0f + 1, 0), H - 1);
        bool valid = (ys >= 0.0f) && (ys <= Hm1) && (xs >= 0.0f) && (xs <= Hm1);
        float w00 = (1.0f - wy) * (1.0f - wx);
        float w01 = (1.0f - wy) * wx;
        float w10 = wy * (1.0f - wx);
        float w11 = wy * wx;
        nfloat4 res;
        if (USE_FP8) {
            const unsigned char* base = feat + ((size_t)lvlOff[l] << 8) + (c4 << 2);
            unsigned ua = *(const unsigned*)(base + ((size_t)(y0  * H + x0 ) << 8));
            unsigned ub = *(const unsigned*)(base + ((size_t)(y0  * H + x1c) << 8));
            unsigned uc = *(const unsigned*)(base + ((size_t)(y1c * H + x0 ) << 8));
            unsigned ud = *(const unsigned*)(base + ((size_t)(y1c * H + x1c) << 8));
            auto a01 = __builtin_amdgcn_cvt_pk_f32_fp8(ua, false);
            auto a23 = __builtin_amdgcn_cvt_pk_f32_fp8(ua, true);
            auto b01 = __builtin_amdgcn_cvt_pk_f32_fp8(ub, false);
            auto b23 = __builtin_amdgcn_cvt_pk_f32_fp8(ub, true);
            auto c01 = __builtin_amdgcn_cvt_pk_f32_fp8(uc, false);
            auto c23 = __builtin_amdgcn_cvt_pk_f32_fp8(uc, true);
            auto d01 = __builtin_amdgcn_cvt_pk_f32_fp8(ud, false);
            auto d23 = __builtin_amdgcn_cvt_pk_f32_fp8(ud, true);
            res.x = w00 * a01[0] + w01 * b01[0] + w10 * c01[0] + w11 * d01[0];
            res.y = w00 * a01[1] + w01 * b01[1] + w10 * c01[1] + w11 * d01[1];
            res.z = w00 * a23[0] + w01 * b23[0] + w10 * c23[0] + w11 * d23[0];
            res.w = w00 * a23[1] + w01 * b23[1] + w10 * c23[1] + w11 * d23[1];
        } else {
            const float* f = fm[l];
            float4 a = ((const float4*)(f + ((size_t)(y0  * H + x0 ) << 8)))[c4];
            float4 b = ((const float4*)(f + ((size_t)(y0  * H + x1c) << 8)))[c4];
            float4 c = ((const float4*)(f + ((size_t)(y1c * H + x0 ) << 8)))[c4];
            float4 d = ((const float4*)(f + ((size_t)(y1c * H + x1c) << 8)))[c4];
            res.x = w00 * a.x + w01 * b.x + w10 * c.x + w11 * d.x;
            res.y = w00 * a.y + w01 * b.y + w10 * c.y + w11 * d.y;
            res.z = w00 * a.z + w01 * b.z + w10 * c.z + w11 * d.z;
            res.w = w00 * a.w + w01 * b.w + w10 * c.w + w11 * d.w;
        }
        if (!valid) { res.x = 0.f; res.y = 0.f; res.z = 0.f; res.w = 0.f; }
        __builtin_nontemporal_store(res, (nfloat4*)(o + l * 256) + c4);
    }
}

extern "C" void kernel_launch(void* const* d_in, const int* in_sizes, int n_in,
                              void* d_out, int out_size, void* d_ws, size_t ws_size,
                              hipStream_t stream) {
    const int*   ishape = (const int*)d_in[0];
    const float* boxes  = (const float*)d_in[1];
    const float* cls    = (const float*)d_in[2];
    const float* p3     = (const float*)d_in[3];
    const float* p4     = (const float*)d_in[4];
    const float* p5     = (const float*)d_in[5];
    const float* p6     = (const float*)d_in[6];
    const float* p7     = (const float*)d_in[7];
    float* out = (float*)d_out;

    int N = in_sizes[2] / NCLS;   // 196416

    char* ws = (char*)d_ws;
    int*      state  = (int*)(ws + WS_STATE);
    int*      hist   = (int*)(ws + WS_HIST);
    int*      gtIdx  = (int*)(ws + WS_GT);
    int*      eqIdx  = (int*)(ws + WS_EQ);
    int*      topIdx = (int*)(ws + WS_TOP);
    float*    boxp   = (float*)(ws + WS_BOXP);
    float*    scores = (float*)(ws + WS_SCORES);
    unsigned* feat   = (unsigned*)(ws + WS_FEAT);

    bool useFp8 = ws_size >= (size_t)WS_FEAT + FP8_BYTES;

    hipLaunchKernelGGL(k_init, dim3(1), dim3(1024), 0, stream, state, hist);
    hipLaunchKernelGGL(k_prep, dim3(useFp8 ? SC_BLOCKS + 5456 : SC_BLOCKS), dim3(256), 0, stream,
                       cls, scores, hist, N, p3, p4, p5, p6, p7, feat);
    for (int pass = 1; pass < 4; ++pass)
        hipLaunchKernelGGL(k_hist, dim3(256), dim3(256), 0, stream, scores, N, hist, pass);
    hipLaunchKernelGGL(k_collect, dim3((N + 255) / 256), dim3(256), 0, stream,
                       scores, N, hist, state, gtIdx, eqIdx);
    hipLaunchKernelGGL(k_sel, dim3(1), dim3(1024), 0, stream,
                       scores, hist, state, gtIdx, eqIdx, boxes, cls, ishape, topIdx, boxp, out);
    if (useFp8)
        hipLaunchKernelGGL((k_roi<1>), dim3(TOPK * NPOS / 4), dim3(256), 0, stream,
                           boxp, topIdx, (const unsigned char*)feat, p3, p4, p5, p6, p7, out);
    else
        hipLaunchKernelGGL((k_roi<0>), dim3(TOPK * NPOS / 4), dim3(256), 0, stream,
                           boxp, topIdx, (const unsigned char*)feat, p3, p4, p5, p6, p7, out);
}

// Round 8
// 198.382 us; speedup vs baseline: 1.5876x; 1.2546x over previous
//
#include <hip/hip_runtime.h>

#define TOPK 500
#define NCLS 80
#define NPOS 196   // 14*14
#define NLEV 5
#define OUT_B_OFF 0
#define OUT_C_OFF 2000
#define OUT_R_OFF 42000

typedef float nfloat4 __attribute__((ext_vector_type(4)));

// ---------------- workspace layout (bytes) ----------------
#define WS_STATE   0          // int[16]: 5=nGt 6=nEq
#define WS_BAR     64         // int[16]: grid barrier counters
#define WS_HIST    128        // int[4][256]
#define WS_GT      8192       // int[512]
#define WS_EQ      12288      // int[1024]
#define WS_TOP     16384      // int[512]
#define WS_BOXP    20480      // float4[512]
#define WS_SCORES  40960      // float[N] (~786 KB)
#define WS_FEAT    (1u << 20) // bf16 feats, 10.7 MB
#define FEAT_PX    21824      // 16384+4096+1024+256+64
#define BF16_BYTES ((size_t)FEAT_PX * 256 * 2)

#define TK_BLOCKS  32

__device__ inline unsigned short f2bf(float f) {
    unsigned u = __float_as_uint(f);
    return (unsigned short)((u + 0x7FFFu + ((u >> 16) & 1u)) >> 16);
}

// fused: blocks [0,SC) scores (block 0 zeroes ctrl: state+bar+hist);
//        blocks [SC,..) convert feats->bf16
#define SC_BLOCKS 768
__global__ __launch_bounds__(256) void k_prep(
    const float* __restrict__ cls, float* __restrict__ scores, int* __restrict__ ctrl, int N,
    const float* __restrict__ p3, const float* __restrict__ p4,
    const float* __restrict__ p5, const float* __restrict__ p6,
    const float* __restrict__ p7, ushort* __restrict__ dst) {
    int b = blockIdx.x;
    int t = threadIdx.x;
    if (b < SC_BLOCKS) {
        if (b == 0) {   // zero state+bar+hist: (64+64+4096)/4 = 1056 ints
            for (int z = t; z < 1056; z += 256) ctrl[z] = 0;
        }
        int i = b * 256 + t;
        if (i < N) {
            const float4* p = (const float4*)(cls + (size_t)i * NCLS);
            float m = -1e30f;
#pragma unroll
            for (int k = 0; k < NCLS / 4; ++k) {
                float4 v = p[k];
                m = fmaxf(m, fmaxf(fmaxf(v.x, v.y), fmaxf(v.z, v.w)));
            }
            scores[i] = m;
        }
    } else {
        int i = (b - SC_BLOCKS) * 256 + t;  // float4 chunk, total 1,396,736
        const int n0 = 1048576, n1 = 262144, n2 = 65536, n3 = 16384;
        const float* src; int off;
        if (i < n0)               { src = p3; off = i; }
        else if (i < n0+n1)       { src = p4; off = i - n0; }
        else if (i < n0+n1+n2)    { src = p5; off = i - n0 - n1; }
        else if (i < n0+n1+n2+n3) { src = p6; off = i - n0 - n1 - n2; }
        else                      { src = p7; off = i - n0 - n1 - n2 - n3; }
        float4 v = ((const float4*)src)[off];
        ushort4 r;
        r.x = f2bf(v.x); r.y = f2bf(v.y); r.z = f2bf(v.z); r.w = f2bf(v.w);
        ((ushort4*)dst)[i] = r;
    }
}

// fused top-k: 4 radix passes (parallel LDS suffix-scan replay) + collect +
// rank-by-count + gather. 32 co-resident blocks, atomic grid barriers.
__global__ __launch_bounds__(1024) void k_topk(
    const float* __restrict__ scores, int N,
    int* hist, int* state, int* bar, int* gtIdx, int* eqIdx,
    const float* __restrict__ boxes, const float* __restrict__ cls,
    const int* __restrict__ ishape,
    int* __restrict__ topIdx, float* __restrict__ boxp, float* __restrict__ out) {
    __shared__ int lh[256];
    __shared__ int ss[256];
    __shared__ int sCh, sK;
    __shared__ unsigned long long key[1024];
    __shared__ int ordTop[TOPK];
    int t = threadIdx.x;
    int gstride = TK_BLOCKS * 1024;
    unsigned prefix = 0;
    int k = TOPK;

    for (int p = 0; p < 4; ++p) {
        int shift = 24 - 8 * p;
        unsigned mask = (p == 0) ? 0u : (0xFFFFFFFFu << (32 - 8 * p));
        if (t < 256) lh[t] = 0;
        __syncthreads();
        for (int i = blockIdx.x * 1024 + t; i < N; i += gstride) {
            unsigned bits = __float_as_uint(scores[i]);
            if ((bits & mask) == prefix)
                atomicAdd(&lh[(bits >> shift) & 0xFF], 1);
        }
        __syncthreads();
        if (t < 256) { int c = lh[t]; if (c) atomicAdd(&hist[(p << 8) + t], c); }
        // ---- grid barrier p ----
        __threadfence();
        __syncthreads();
        if (t == 0) {
            atomicAdd(&bar[p], 1);
            while (atomicAdd(&bar[p], 0) < TK_BLOCKS) __builtin_amdgcn_s_sleep(8);
            __threadfence();
        }
        __syncthreads();
        // ---- parallel replay: LDS suffix-sum + pick ----
        if (t < 256) ss[t] = atomicAdd(&hist[(p << 8) + t], 0);
        __syncthreads();
        for (int o = 1; o < 256; o <<= 1) {
            int v = 0;
            if (t < 256 && t + o < 256) v = ss[t + o];
            __syncthreads();
            if (t < 256) ss[t] += v;
            __syncthreads();
        }
        if (t < 256 && ss[t] >= k && (t == 255 || ss[t + 1] < k)) {
            sCh = t;
            sK = k - ((t == 255) ? 0 : ss[t + 1]);
        }
        __syncthreads();
        prefix |= ((unsigned)sCh) << shift;
        k = sK;
    }

    // ---- collect candidates ----
    unsigned T = prefix;
    for (int i = blockIdx.x * 1024 + t; i < N; i += gstride) {
        unsigned bits = __float_as_uint(scores[i]);
        if (bits > T) {
            int p2 = atomicAdd(&state[5], 1);
            if (p2 < 512) atomicExch(&gtIdx[p2], i);
        } else if (bits == T) {
            int p2 = atomicAdd(&state[6], 1);
            if (p2 < 1024) atomicExch(&eqIdx[p2], i);
        }
    }
    // ---- grid barrier 4 ----
    __threadfence();
    __syncthreads();
    if (t == 0) {
        atomicAdd(&bar[4], 1);
        while (atomicAdd(&bar[4], 0) < TK_BLOCKS) __builtin_amdgcn_s_sleep(8);
        __threadfence();
    }
    __syncthreads();
    if (blockIdx.x != 0) return;

    // ---- block 0: rank by counting, write topIdx/boxp, gather boxes+classes ----
    int cntGt  = min(atomicAdd(&state[5], 0), 512);
    int nEq    = atomicAdd(&state[6], 0);
    int eqTake = min(min(nEq, 1024), 1024 - cntGt);
    int total  = cntGt + eqTake;
    {
        unsigned long long kk = 0ull;
        if (t < cntGt) {
            int idx = atomicAdd(&gtIdx[t], 0);
            kk = ((unsigned long long)__float_as_uint(scores[idx]) << 32) | (unsigned)(~idx);
        } else if (t < total) {
            int idx = atomicAdd(&eqIdx[t - cntGt], 0);
            kk = ((unsigned long long)T << 32) | (unsigned)(~idx);
        }
        key[t] = kk;
    }
    __syncthreads();
    float hf = (float)ishape[1], wf = (float)ishape[2];
    if (t < total) {
        unsigned long long me = key[t];
        int r = 0;
        for (int j2 = 0; j2 < 1024; ++j2) r += (key[j2] > me);
        if (r < TOPK) {
            int idx = (int)(~(unsigned)(me & 0xFFFFFFFFull));
            ordTop[r] = idx;
            topIdx[r] = idx;
            float bx1 = boxes[idx * 4 + 0], by1 = boxes[idx * 4 + 1];
            float bx2 = boxes[idx * 4 + 2], by2 = boxes[idx * 4 + 3];
            nfloat4 bp;
            bp.x = by1 / hf; bp.y = bx1 / wf;
            bp.z = (by2 - by1) / hf; bp.w = (bx2 - bx1) / wf;
            *(nfloat4*)(boxp + 4 * r) = bp;
        }
    }
    __syncthreads();
    for (int e = t; e < TOPK * (NCLS + 4); e += 1024) {
        int j2 = e / (NCLS + 4);
        int k2 = e - j2 * (NCLS + 4);
        int idx = ordTop[j2];
        if (k2 < 4) out[OUT_B_OFF + j2 * 4 + k2] = boxes[(size_t)idx * 4 + k2];
        else        out[OUT_C_OFF + j2 * NCLS + (k2 - 4)] = cls[(size_t)idx * NCLS + (k2 - 4)];
    }
}

// ROI: 4 positions / 256-thread block; 64 lanes/position, 4 channels/lane. bf16 feats.
template <int USE_BF16>
__global__ __launch_bounds__(256) void k_roi(
    const float* __restrict__ boxp, const int* __restrict__ topIdx,
    const ushort* __restrict__ feat,
    const float* __restrict__ f0, const float* __restrict__ f1,
    const float* __restrict__ f2, const float* __restrict__ f3,
    const float* __restrict__ f4,
    float* __restrict__ out) {
    const int lvlOff[5] = {0, 16384, 20480, 21504, 21760};
    // bijective XCD-chunked swizzle (m204)
    int nwg = gridDim.x;
    int q = nwg >> 3, r = nwg & 7;
    int orig = blockIdx.x;
    int xcd = orig & 7, i8 = orig >> 3;
    int wg = (xcd < r ? xcd * (q + 1) : r * (q + 1) + (xcd - r) * q) + i8;
    int P  = wg * 4 + (threadIdx.x >> 6);
    int c4 = threadIdx.x & 63;
    int j = P / NPOS;
    int pos = P - j * NPOS;
    int y = pos / 14, x = pos - (pos / 14) * 14;
    nfloat4 bp = *(const nfloat4*)(boxp + 4 * j);
    float ty = (float)y / 13.0f;
    float tx = (float)x / 13.0f;
    const float* fm[5] = {f0, f1, f2, f3, f4};
    float* o = out + OUT_R_OFF + (size_t)P * (NLEV * 256);
#pragma unroll
    for (int l = 0; l < NLEV; ++l) {
        int H = 128 >> l;
        float Hm1 = (float)(H - 1);
        float ys = (bp.x + ty * bp.z) * Hm1;
        float xs = (bp.y + tx * bp.w) * Hm1;
        float y0f = floorf(ys), x0f = floorf(xs);
        float wy = ys - y0f, wx = xs - x0f;
        int y0  = min(max((int)y0f, 0), H - 1);
        int y1c = min(max((int)y0f + 1, 0), H - 1);
        int x0  = min(max((int)x0f, 0), H - 1);
        int x1c = min(max((int)x0f + 1, 0), H - 1);
        bool valid = (ys >= 0.0f) && (ys <= Hm1) && (xs >= 0.0f) && (xs <= Hm1);
        float w00 = (1.0f - wy) * (1.0f - wx);
        float w01 = (1.0f - wy) * wx;
        float w10 = wy * (1.0f - wx);
        float w11 = wy * wx;
        nfloat4 res;
        if (USE_BF16) {
            const ushort* base = feat + ((size_t)lvlOff[l] << 8);
            ushort4 a = ((const ushort4*)(base + ((size_t)(y0  * H + x0 ) << 8)))[c4];
            ushort4 b = ((const ushort4*)(base + ((size_t)(y0  * H + x1c) << 8)))[c4];
            ushort4 c = ((const ushort4*)(base + ((size_t)(y1c * H + x0 ) << 8)))[c4];
            ushort4 d = ((const ushort4*)(base + ((size_t)(y1c * H + x1c) << 8)))[c4];
#define BF(u) __uint_as_float(((unsigned)(u)) << 16)
            res.x = w00 * BF(a.x) + w01 * BF(b.x) + w10 * BF(c.x) + w11 * BF(d.x);
            res.y = w00 * BF(a.y) + w01 * BF(b.y) + w10 * BF(c.y) + w11 * BF(d.y);
            res.z = w00 * BF(a.z) + w01 * BF(b.z) + w10 * BF(c.z) + w11 * BF(d.z);
            res.w = w00 * BF(a.w) + w01 * BF(b.w) + w10 * BF(c.w) + w11 * BF(d.w);
#undef BF
        } else {
            const float* f = fm[l];
            float4 a = ((const float4*)(f + ((size_t)(y0  * H + x0 ) << 8)))[c4];
            float4 b = ((const float4*)(f + ((size_t)(y0  * H + x1c) << 8)))[c4];
            float4 c = ((const float4*)(f + ((size_t)(y1c * H + x0 ) << 8)))[c4];
            float4 d = ((const float4*)(f + ((size_t)(y1c * H + x1c) << 8)))[c4];
            res.x = w00 * a.x + w01 * b.x + w10 * c.x + w11 * d.x;
            res.y = w00 * a.y + w01 * b.y + w10 * c.y + w11 * d.y;
            res.z = w00 * a.z + w01 * b.z + w10 * c.z + w11 * d.z;
            res.w = w00 * a.w + w01 * b.w + w10 * c.w + w11 * d.w;
        }
        if (!valid) { res.x = 0.f; res.y = 0.f; res.z = 0.f; res.w = 0.f; }
        __builtin_nontemporal_store(res, (nfloat4*)(o + l * 256) + c4);
    }
}

extern "C" void kernel_launch(void* const* d_in, const int* in_sizes, int n_in,
                              void* d_out, int out_size, void* d_ws, size_t ws_size,
                              hipStream_t stream) {
    const int*   ishape = (const int*)d_in[0];
    const float* boxes  = (const float*)d_in[1];
    const float* cls    = (const float*)d_in[2];
    const float* p3     = (const float*)d_in[3];
    const float* p4     = (const float*)d_in[4];
    const float* p5     = (const float*)d_in[5];
    const float* p6     = (const float*)d_in[6];
    const float* p7     = (const float*)d_in[7];
    float* out = (float*)d_out;

    int N = in_sizes[2] / NCLS;   // 196416

    char* ws = (char*)d_ws;
    int*    state  = (int*)(ws + WS_STATE);
    int*    bar    = (int*)(ws + WS_BAR);
    int*    hist   = (int*)(ws + WS_HIST);
    int*    gtIdx  = (int*)(ws + WS_GT);
    int*    eqIdx  = (int*)(ws + WS_EQ);
    int*    topIdx = (int*)(ws + WS_TOP);
    float*  boxp   = (float*)(ws + WS_BOXP);
    float*  scores = (float*)(ws + WS_SCORES);
    ushort* feat   = (ushort*)(ws + WS_FEAT);

    bool useBf16 = ws_size >= (size_t)WS_FEAT + BF16_BYTES;

    hipLaunchKernelGGL(k_prep, dim3(useBf16 ? SC_BLOCKS + 5456 : SC_BLOCKS), dim3(256), 0, stream,
                       cls, scores, state, N, p3, p4, p5, p6, p7, feat);
    hipLaunchKernelGGL(k_topk, dim3(TK_BLOCKS), dim3(1024), 0, stream,
                       scores, N, hist, state, bar, gtIdx, eqIdx,
                       boxes, cls, ishape, topIdx, boxp, out);
    if (useBf16)
        hipLaunchKernelGGL((k_roi<1>), dim3(TOPK * NPOS / 4), dim3(256), 0, stream,
                           boxp, topIdx, feat, p3, p4, p5, p6, p7, out);
    else
        hipLaunchKernelGGL((k_roi<0>), dim3(TOPK * NPOS / 4), dim3(256), 0, stream,
                           boxp, topIdx, feat, p3, p4, p5, p6, p7, out);
}

// Round 9
// 144.386 us; speedup vs baseline: 2.1813x; 1.3740x over previous
//
#include <hip/hip_runtime.h>

#define TOPK 500
#define NCLS 80
#define NPOS 196   // 14*14
#define NLEV 5
#define OUT_B_OFF 0
#define OUT_C_OFF 2000
#define OUT_R_OFF 42000

typedef float nfloat4 __attribute__((ext_vector_type(4)));
typedef unsigned long long u64;

#define SC_BLOCKS 768
#define SLICE     32
#define CUT       0x3F7FF000u   // score >= 0.999756 -> E[cands] ~3800
#define CAP_M     5632

// ---------------- workspace layout (bytes) ----------------
#define WS_CNT    0            // int candCnt[768]
#define WS_TOP    4096         // int topIdx[512]
#define WS_BOXP   8192         // float4[512]
#define WS_CAND   16384        // u64 cand[768*32] (196608 B)
#define WS_SCORES 262144       // float[N] (785664 B)
#define WS_FEAT   (1u << 20)   // bf16 feats, 10.7 MB
#define FEAT_PX   21824        // 16384+4096+1024+256+64
#define BF16_BYTES ((size_t)FEAT_PX * 256 * 2)

__device__ inline unsigned short f2bf(float f) {
    unsigned u = __float_as_uint(f);
    return (unsigned short)((u + 0x7FFFu + ((u >> 16) & 1u)) >> 16);
}

// fused: blocks [0,SC) scores + candidate append (per-block slice, plain stores);
//        blocks [SC,..) convert feats->bf16
__global__ __launch_bounds__(256) void k_prep(
    const float* __restrict__ cls, float* __restrict__ scores,
    int* __restrict__ candCnt, u64* __restrict__ cand, int N,
    const float* __restrict__ p3, const float* __restrict__ p4,
    const float* __restrict__ p5, const float* __restrict__ p6,
    const float* __restrict__ p7, ushort* __restrict__ dst) {
    int b = blockIdx.x;
    int t = threadIdx.x;
    if (b < SC_BLOCKS) {
        __shared__ int lcnt;
        __shared__ u64 stage[SLICE];
        if (t == 0) lcnt = 0;
        __syncthreads();
        int i = b * 256 + t;
        if (i < N) {
            const float4* p = (const float4*)(cls + (size_t)i * NCLS);
            float m = -1e30f;
#pragma unroll
            for (int k = 0; k < NCLS / 4; ++k) {
                float4 v = p[k];
                m = fmaxf(m, fmaxf(fmaxf(v.x, v.y), fmaxf(v.z, v.w)));
            }
            scores[i] = m;
            unsigned bits = __float_as_uint(m);
            if (bits >= CUT) {
                int p2 = atomicAdd(&lcnt, 1);
                if (p2 < SLICE) stage[p2] = ((u64)bits << 32) | (unsigned)(~i);
            }
        }
        __syncthreads();
        if (t == 0) candCnt[b] = lcnt;                 // raw count (>SLICE => fallback flag)
        if (t < min(lcnt, SLICE)) cand[b * SLICE + t] = stage[t];
    } else {
        int i = (b - SC_BLOCKS) * 256 + t;  // float4 chunk, total 1,396,736
        const int n0 = 1048576, n1 = 262144, n2 = 65536, n3 = 16384;
        const float* src; int off;
        if (i < n0)               { src = p3; off = i; }
        else if (i < n0+n1)       { src = p4; off = i - n0; }
        else if (i < n0+n1+n2)    { src = p5; off = i - n0 - n1; }
        else if (i < n0+n1+n2+n3) { src = p6; off = i - n0 - n1 - n2; }
        else                      { src = p7; off = i - n0 - n1 - n2 - n3; }
        float4 v = ((const float4*)src)[off];
        ushort4 r;
        r.x = f2bf(v.x); r.y = f2bf(v.y); r.z = f2bf(v.z); r.w = f2bf(v.w);
        ((ushort4*)dst)[i] = r;
    }
}

// single-block top-k over the compact candidate list (fallback: full-N radix).
__global__ __launch_bounds__(1024) void k_topk(
    const float* __restrict__ scores, int N,
    const int* __restrict__ candCnt, const u64* __restrict__ cand,
    const float* __restrict__ boxes, const float* __restrict__ cls,
    const int* __restrict__ ishape,
    int* __restrict__ topIdx, float* __restrict__ boxp, float* __restrict__ out) {
    __shared__ u64 dense[CAP_M];
    __shared__ int sv[768];
    __shared__ int hist[256];
    __shared__ int ss[256];
    __shared__ u64 key[1024];
    __shared__ int ordTop[TOPK];
    __shared__ int sBad, sCh, sK, nTot;
    __shared__ unsigned sAnd, sOr;
    int t = threadIdx.x;
    if (t == 0) { sBad = 0; nTot = 0; sAnd = 0xFFFFFFFFu; sOr = 0u; }
    key[t] = 0ull;
    int myv = 0;
    if (t < 768) {
        int c = candCnt[t];
        if (c > SLICE) atomicOr(&sBad, 1);
        myv = min(c, SLICE);
        sv[t] = myv;
    }
    __syncthreads();
    // inclusive scan over 768 counts
    for (int o = 1; o < 1024; o <<= 1) {
        int x = 0;
        if (t < 768 && t >= o) x = sv[t - o];
        __syncthreads();
        if (t < 768 && t >= o) sv[t] += x;
        __syncthreads();
    }
    int M = sv[767];
    bool valid = (!sBad) && (M >= TOPK) && (M <= CAP_M);
    if (valid && t < 768) {
        int off = sv[t] - myv;
        for (int s = 0; s < myv; ++s) dense[off + s] = cand[t * SLICE + s];
    }
    __syncthreads();

    unsigned prefix = 0;
    int k = TOPK;
    if (valid) {
        // AND/OR reduce of score bits -> skip constant-digit passes
        unsigned ma = 0xFFFFFFFFu, mo = 0u;
        for (int q = t; q < M; q += 1024) {
            unsigned b = (unsigned)(dense[q] >> 32);
            ma &= b; mo |= b;
        }
        for (int o = 32; o; o >>= 1) { ma &= __shfl_down(ma, o); mo |= __shfl_down(mo, o); }
        if ((t & 63) == 0) { atomicAnd(&sAnd, ma); atomicOr(&sOr, mo); }
        __syncthreads();
        unsigned ga = sAnd, go = sOr;
        for (int p = 0; p < 4; ++p) {
            int shift = 24 - 8 * p;
            unsigned cA = (ga >> shift) & 255u, cO = (go >> shift) & 255u;
            if (cA == cO) { prefix |= cA << shift; continue; }   // digit constant
            unsigned mask = (p == 0) ? 0u : (0xFFFFFFFFu << (32 - 8 * p));
            if (t < 256) hist[t] = 0;
            __syncthreads();
            for (int q = t; q < M; q += 1024) {
                unsigned b = (unsigned)(dense[q] >> 32);
                if ((b & mask) == prefix) atomicAdd(&hist[(b >> shift) & 255u], 1);
            }
            __syncthreads();
            if (t < 256) ss[t] = hist[t];
            __syncthreads();
            for (int o = 1; o < 256; o <<= 1) {
                int v2 = 0;
                if (t < 256 && t + o < 256) v2 = ss[t + o];
                __syncthreads();
                if (t < 256) ss[t] += v2;
                __syncthreads();
            }
            if (t < 256 && ss[t] >= k && (t == 255 || ss[t + 1] < k)) {
                sCh = t; sK = k - ((t == 255) ? 0 : ss[t + 1]);
            }
            __syncthreads();
            prefix |= ((unsigned)sCh) << shift;
            k = sK;
            __syncthreads();
        }
        // collect all keys with score-bits >= T
        for (int q = t; q < M; q += 1024) {
            u64 kk = dense[q];
            if ((unsigned)(kk >> 32) >= prefix) {
                int p2 = atomicAdd(&nTot, 1);
                if (p2 < 1024) key[p2] = kk;
            }
        }
    } else {
        // fallback: full radix over scores[0..N) in one block (correct, slow, never hit on bench)
        for (int p = 0; p < 4; ++p) {
            int shift = 24 - 8 * p;
            unsigned mask = (p == 0) ? 0u : (0xFFFFFFFFu << (32 - 8 * p));
            if (t < 256) hist[t] = 0;
            __syncthreads();
            for (int q = t; q < N; q += 1024) {
                unsigned b = __float_as_uint(scores[q]);
                if ((b & mask) == prefix) atomicAdd(&hist[(b >> shift) & 255u], 1);
            }
            __syncthreads();
            if (t < 256) ss[t] = hist[t];
            __syncthreads();
            for (int o = 1; o < 256; o <<= 1) {
                int v2 = 0;
                if (t < 256 && t + o < 256) v2 = ss[t + o];
                __syncthreads();
                if (t < 256) ss[t] += v2;
                __syncthreads();
            }
            if (t < 256 && ss[t] >= k && (t == 255 || ss[t + 1] < k)) {
                sCh = t; sK = k - ((t == 255) ? 0 : ss[t + 1]);
            }
            __syncthreads();
            prefix |= ((unsigned)sCh) << shift;
            k = sK;
            __syncthreads();
        }
        for (int q = t; q < N; q += 1024) {
            unsigned b = __float_as_uint(scores[q]);
            if (b >= prefix) {
                int p2 = atomicAdd(&nTot, 1);
                if (p2 < 1024) key[p2] = ((u64)b << 32) | (unsigned)(~q);
            }
        }
    }
    __syncthreads();
    // rank by counting (order-invariant, exact jax tie-break: score desc, idx asc)
    float hf = (float)ishape[1], wf = (float)ishape[2];
    u64 me = key[t];
    if (me) {
        int r = 0;
        for (int j = 0; j < 1024; ++j) r += (key[j] > me);
        if (r < TOPK) {
            int idx = (int)(~(unsigned)(me & 0xFFFFFFFFull));
            ordTop[r] = idx;
            topIdx[r] = idx;
            float bx1 = boxes[idx * 4 + 0], by1 = boxes[idx * 4 + 1];
            float bx2 = boxes[idx * 4 + 2], by2 = boxes[idx * 4 + 3];
            nfloat4 bp;
            bp.x = by1 / hf; bp.y = bx1 / wf;
            bp.z = (by2 - by1) / hf; bp.w = (bx2 - bx1) / wf;
            *(nfloat4*)(boxp + 4 * r) = bp;
        }
    }
    __syncthreads();
    for (int e = t; e < TOPK * (NCLS + 4); e += 1024) {
        int j = e / (NCLS + 4);
        int k2 = e - j * (NCLS + 4);
        int idx = ordTop[j];
        if (k2 < 4) out[OUT_B_OFF + j * 4 + k2] = boxes[(size_t)idx * 4 + k2];
        else        out[OUT_C_OFF + j * NCLS + (k2 - 4)] = cls[(size_t)idx * NCLS + (k2 - 4)];
    }
}

// ROI: 4 positions / 256-thread block; 64 lanes/position, 4 channels/lane. bf16 feats.
template <int USE_BF16>
__global__ __launch_bounds__(256) void k_roi(
    const float* __restrict__ boxp, const int* __restrict__ topIdx,
    const ushort* __restrict__ feat,
    const float* __restrict__ f0, const float* __restrict__ f1,
    const float* __restrict__ f2, const float* __restrict__ f3,
    const float* __restrict__ f4,
    float* __restrict__ out) {
    const int lvlOff[5] = {0, 16384, 20480, 21504, 21760};
    // bijective XCD-chunked swizzle (m204)
    int nwg = gridDim.x;
    int q = nwg >> 3, r = nwg & 7;
    int orig = blockIdx.x;
    int xcd = orig & 7, i8 = orig >> 3;
    int wg = (xcd < r ? xcd * (q + 1) : r * (q + 1) + (xcd - r) * q) + i8;
    int P  = wg * 4 + (threadIdx.x >> 6);
    int c4 = threadIdx.x & 63;
    int j = P / NPOS;
    int pos = P - j * NPOS;
    int y = pos / 14, x = pos - (pos / 14) * 14;
    nfloat4 bp = *(const nfloat4*)(boxp + 4 * j);
    float ty = (float)y / 13.0f;
    float tx = (float)x / 13.0f;
    const float* fm[5] = {f0, f1, f2, f3, f4};
    float* o = out + OUT_R_OFF + (size_t)P * (NLEV * 256);
#pragma unroll
    for (int l = 0; l < NLEV; ++l) {
        int H = 128 >> l;
        float Hm1 = (float)(H - 1);
        float ys = (bp.x + ty * bp.z) * Hm1;
        float xs = (bp.y + tx * bp.w) * Hm1;
        float y0f = floorf(ys), x0f = floorf(xs);
        float wy = ys - y0f, wx = xs - x0f;
        int y0  = min(max((int)y0f, 0), H - 1);
        int y1c = min(max((int)y0f + 1, 0), H - 1);
        int x0  = min(max((int)x0f, 0), H - 1);
        int x1c = min(max((int)x0f + 1, 0), H - 1);
        bool valid = (ys >= 0.0f) && (ys <= Hm1) && (xs >= 0.0f) && (xs <= Hm1);
        float w00 = (1.0f - wy) * (1.0f - wx);
        float w01 = (1.0f - wy) * wx;
        float w10 = wy * (1.0f - wx);
        float w11 = wy * wx;
        nfloat4 res;
        if (USE_BF16) {
            const ushort* base = feat + ((size_t)lvlOff[l] << 8);
            ushort4 a = ((const ushort4*)(base + ((size_t)(y0  * H + x0 ) << 8)))[c4];
            ushort4 b = ((const ushort4*)(base + ((size_t)(y0  * H + x1c) << 8)))[c4];
            ushort4 c = ((const ushort4*)(base + ((size_t)(y1c * H + x0 ) << 8)))[c4];
            ushort4 d = ((const ushort4*)(base + ((size_t)(y1c * H + x1c) << 8)))[c4];
#define BF(u) __uint_as_float(((unsigned)(u)) << 16)
            res.x = w00 * BF(a.x) + w01 * BF(b.x) + w10 * BF(c.x) + w11 * BF(d.x);
            res.y = w00 * BF(a.y) + w01 * BF(b.y) + w10 * BF(c.y) + w11 * BF(d.y);
            res.z = w00 * BF(a.z) + w01 * BF(b.z) + w10 * BF(c.z) + w11 * BF(d.z);
            res.w = w00 * BF(a.w) + w01 * BF(b.w) + w10 * BF(c.w) + w11 * BF(d.w);
#undef BF
        } else {
            const float* f = fm[l];
            float4 a = ((const float4*)(f + ((size_t)(y0  * H + x0 ) << 8)))[c4];
            float4 b = ((const float4*)(f + ((size_t)(y0  * H + x1c) << 8)))[c4];
            float4 c = ((const float4*)(f + ((size_t)(y1c * H + x0 ) << 8)))[c4];
            float4 d = ((const float4*)(f + ((size_t)(y1c * H + x1c) << 8)))[c4];
            res.x = w00 * a.x + w01 * b.x + w10 * c.x + w11 * d.x;
            res.y = w00 * a.y + w01 * b.y + w10 * c.y + w11 * d.y;
            res.z = w00 * a.z + w01 * b.z + w10 * c.z + w11 * d.z;
            res.w = w00 * a.w + w01 * b.w + w10 * c.w + w11 * d.w;
        }
        if (!valid) { res.x = 0.f; res.y = 0.f; res.z = 0.f; res.w = 0.f; }
        __builtin_nontemporal_store(res, (nfloat4*)(o + l * 256) + c4);
    }
}

extern "C" void kernel_launch(void* const* d_in, const int* in_sizes, int n_in,
                              void* d_out, int out_size, void* d_ws, size_t ws_size,
                              hipStream_t stream) {
    const int*   ishape = (const int*)d_in[0];
    const float* boxes  = (const float*)d_in[1];
    const float* cls    = (const float*)d_in[2];
    const float* p3     = (const float*)d_in[3];
    const float* p4     = (const float*)d_in[4];
    const float* p5     = (const float*)d_in[5];
    const float* p6     = (const float*)d_in[6];
    const float* p7     = (const float*)d_in[7];
    float* out = (float*)d_out;

    int N = in_sizes[2] / NCLS;   // 196416

    char* ws = (char*)d_ws;
    int*    candCnt = (int*)(ws + WS_CNT);
    int*    topIdx  = (int*)(ws + WS_TOP);
    float*  boxp    = (float*)(ws + WS_BOXP);
    u64*    cand    = (u64*)(ws + WS_CAND);
    float*  scores  = (float*)(ws + WS_SCORES);
    ushort* feat    = (ushort*)(ws + WS_FEAT);

    bool useBf16 = ws_size >= (size_t)WS_FEAT + BF16_BYTES;

    hipLaunchKernelGGL(k_prep, dim3(useBf16 ? SC_BLOCKS + 5456 : SC_BLOCKS), dim3(256), 0, stream,
                       cls, scores, candCnt, cand, N, p3, p4, p5, p6, p7, feat);
    hipLaunchKernelGGL(k_topk, dim3(1), dim3(1024), 0, stream,
                       scores, N, candCnt, cand, boxes, cls, ishape, topIdx, boxp, out);
    if (useBf16)
        hipLaunchKernelGGL((k_roi<1>), dim3(TOPK * NPOS / 4), dim3(256), 0, stream,
                           boxp, topIdx, feat, p3, p4, p5, p6, p7, out);
    else
        hipLaunchKernelGGL((k_roi<0>), dim3(TOPK * NPOS / 4), dim3(256), 0, stream,
                           boxp, topIdx, feat, p3, p4, p5, p6, p7, out);
}

// Round 10
// 143.541 us; speedup vs baseline: 2.1941x; 1.0059x over previous
//
#include <hip/hip_runtime.h>

#define TOPK 500
#define NCLS 80
#define NPOS 196   // 14*14
#define NLEV 5
#define OUT_B_OFF 0
#define OUT_C_OFF 2000
#define OUT_R_OFF 42000

typedef float nfloat4 __attribute__((ext_vector_type(4)));
typedef unsigned long long u64;

#define SC_BLOCKS 768
#define SLICE     32
#define CUT       0x3F7FF000u   // score >= 0.999756 -> E[cands] ~3800
#define CAP_M     5632

// ---------------- workspace layout (bytes) ----------------
#define WS_CNT    0            // int candCnt[768]
#define WS_TOP    4096         // int topIdx[512]
#define WS_BOXP   8192         // float4[512]
#define WS_CAND   16384        // u64 cand[768*32]
#define WS_SCORES 262144       // float[N]
#define WS_FEAT   (1u << 20)   // bf16 feats, 10.7 MB
#define FEAT_PX   21824        // 16384+4096+1024+256+64
#define BF16_BYTES ((size_t)FEAT_PX * 256 * 2)

#define CVT_TOTAL 1396736      // float4 chunks over all 5 maps
#define CVT_BLOCKS (CVT_TOTAL / 1024)   // 1364

__device__ inline unsigned short f2bf(float f) {
    unsigned u = __float_as_uint(f);
    return (unsigned short)((u + 0x7FFFu + ((u >> 16) & 1u)) >> 16);
}

// scores + candidate append. 4 lanes per box (coalesced 64B granules), shfl reduce.
__global__ __launch_bounds__(256) void k_prep(
    const float* __restrict__ cls, float* __restrict__ scores,
    int* __restrict__ candCnt, u64* __restrict__ cand, int N) {
    __shared__ int lcnt;
    __shared__ u64 stage[SLICE];
    int b = blockIdx.x, t = threadIdx.x;
    if (t == 0) lcnt = 0;
    __syncthreads();
    int g = t >> 2, q = t & 3;
#pragma unroll
    for (int it = 0; it < 4; ++it) {
        int i = b * 256 + it * 64 + g;
        if (i < N) {
            const float4* p = (const float4*)(cls + (size_t)i * NCLS);
            float m = -1e30f;
#pragma unroll
            for (int j2 = 0; j2 < 5; ++j2) {
                float4 v = p[j2 * 4 + q];
                m = fmaxf(m, fmaxf(fmaxf(v.x, v.y), fmaxf(v.z, v.w)));
            }
            m = fmaxf(m, __shfl_xor(m, 1));
            m = fmaxf(m, __shfl_xor(m, 2));
            if (q == 0) {
                scores[i] = m;
                unsigned bits = __float_as_uint(m);
                if (bits >= CUT) {
                    int p2 = atomicAdd(&lcnt, 1);
                    if (p2 < SLICE) stage[p2] = ((u64)bits << 32) | (unsigned)(~i);
                }
            }
        }
    }
    __syncthreads();
    if (t == 0) candCnt[b] = lcnt;
    if (t < min(lcnt, SLICE)) cand[b * SLICE + t] = stage[t];
}

// block 0: top-k over compact candidates (fallback: full-N radix);
// blocks 1..: convert feature maps f32 -> bf16 (overlaps top-k).
__global__ __launch_bounds__(1024) void k_topk(
    const float* __restrict__ scores, int N,
    const int* __restrict__ candCnt, const u64* __restrict__ cand,
    const float* __restrict__ boxes, const float* __restrict__ cls,
    const int* __restrict__ ishape,
    int* __restrict__ topIdx, float* __restrict__ boxp, float* __restrict__ out,
    const float* __restrict__ p3, const float* __restrict__ p4,
    const float* __restrict__ p5, const float* __restrict__ p6,
    const float* __restrict__ p7, ushort* __restrict__ fdst) {
    int t = threadIdx.x;
    if (blockIdx.x != 0) {
        int i = (int)(blockIdx.x - 1) * 1024 + t;
        const int n0 = 1048576, n1 = 262144, n2 = 65536, n3 = 16384;
        const float* src; int off;
        if (i < n0)               { src = p3; off = i; }
        else if (i < n0+n1)       { src = p4; off = i - n0; }
        else if (i < n0+n1+n2)    { src = p5; off = i - n0 - n1; }
        else if (i < n0+n1+n2+n3) { src = p6; off = i - n0 - n1 - n2; }
        else                      { src = p7; off = i - n0 - n1 - n2 - n3; }
        float4 v = ((const float4*)src)[off];
        ushort4 r;
        r.x = f2bf(v.x); r.y = f2bf(v.y); r.z = f2bf(v.z); r.w = f2bf(v.w);
        ((ushort4*)fdst)[i] = r;
        return;
    }
    __shared__ u64 dense[CAP_M];
    __shared__ int sv[768];
    __shared__ int hist[256];
    __shared__ int ss[256];
    __shared__ u64 key[1024];
    __shared__ int ordTop[TOPK];
    __shared__ int sBad, sCh, sK, nTot;
    __shared__ unsigned sAnd, sOr;
    if (t == 0) { sBad = 0; nTot = 0; sAnd = 0xFFFFFFFFu; sOr = 0u; }
    key[t] = 0ull;
    int myv = 0;
    if (t < 768) {
        int c = candCnt[t];
        if (c > SLICE) atomicOr(&sBad, 1);
        myv = min(c, SLICE);
        sv[t] = myv;
    }
    __syncthreads();
    for (int o = 1; o < 1024; o <<= 1) {
        int x = 0;
        if (t < 768 && t >= o) x = sv[t - o];
        __syncthreads();
        if (t < 768 && t >= o) sv[t] += x;
        __syncthreads();
    }
    int M = sv[767];
    bool valid = (!sBad) && (M >= TOPK) && (M <= CAP_M);
    if (valid && t < 768) {
        int off = sv[t] - myv;
        for (int s = 0; s < myv; ++s) dense[off + s] = cand[t * SLICE + s];
    }
    __syncthreads();

    unsigned prefix = 0;
    int k = TOPK;
    if (valid) {
        unsigned ma = 0xFFFFFFFFu, mo = 0u;
        for (int q = t; q < M; q += 1024) {
            unsigned b = (unsigned)(dense[q] >> 32);
            ma &= b; mo |= b;
        }
        for (int o = 32; o; o >>= 1) { ma &= __shfl_down(ma, o); mo |= __shfl_down(mo, o); }
        if ((t & 63) == 0) { atomicAnd(&sAnd, ma); atomicOr(&sOr, mo); }
        __syncthreads();
        unsigned ga = sAnd, go = sOr;
        for (int p = 0; p < 4; ++p) {
            int shift = 24 - 8 * p;
            unsigned cA = (ga >> shift) & 255u, cO = (go >> shift) & 255u;
            if (cA == cO) { prefix |= cA << shift; continue; }
            unsigned mask = (p == 0) ? 0u : (0xFFFFFFFFu << (32 - 8 * p));
            if (t < 256) hist[t] = 0;
            __syncthreads();
            for (int q = t; q < M; q += 1024) {
                unsigned b = (unsigned)(dense[q] >> 32);
                if ((b & mask) == prefix) atomicAdd(&hist[(b >> shift) & 255u], 1);
            }
            __syncthreads();
            if (t < 256) ss[t] = hist[t];
            __syncthreads();
            for (int o = 1; o < 256; o <<= 1) {
                int v2 = 0;
                if (t < 256 && t + o < 256) v2 = ss[t + o];
                __syncthreads();
                if (t < 256) ss[t] += v2;
                __syncthreads();
            }
            if (t < 256 && ss[t] >= k && (t == 255 || ss[t + 1] < k)) {
                sCh = t; sK = k - ((t == 255) ? 0 : ss[t + 1]);
            }
            __syncthreads();
            prefix |= ((unsigned)sCh) << shift;
            k = sK;
            __syncthreads();
        }
        for (int q = t; q < M; q += 1024) {
            u64 kk = dense[q];
            if ((unsigned)(kk >> 32) >= prefix) {
                int p2 = atomicAdd(&nTot, 1);
                if (p2 < 1024) key[p2] = kk;
            }
        }
    } else {
        for (int p = 0; p < 4; ++p) {
            int shift = 24 - 8 * p;
            unsigned mask = (p == 0) ? 0u : (0xFFFFFFFFu << (32 - 8 * p));
            if (t < 256) hist[t] = 0;
            __syncthreads();
            for (int q = t; q < N; q += 1024) {
                unsigned b = __float_as_uint(scores[q]);
                if ((b & mask) == prefix) atomicAdd(&hist[(b >> shift) & 255u], 1);
            }
            __syncthreads();
            if (t < 256) ss[t] = hist[t];
            __syncthreads();
            for (int o = 1; o < 256; o <<= 1) {
                int v2 = 0;
                if (t < 256 && t + o < 256) v2 = ss[t + o];
                __syncthreads();
                if (t < 256) ss[t] += v2;
                __syncthreads();
            }
            if (t < 256 && ss[t] >= k && (t == 255 || ss[t + 1] < k)) {
                sCh = t; sK = k - ((t == 255) ? 0 : ss[t + 1]);
            }
            __syncthreads();
            prefix |= ((unsigned)sCh) << shift;
            k = sK;
            __syncthreads();
        }
        for (int q = t; q < N; q += 1024) {
            unsigned b = __float_as_uint(scores[q]);
            if (b >= prefix) {
                int p2 = atomicAdd(&nTot, 1);
                if (p2 < 1024) key[p2] = ((u64)b << 32) | (unsigned)(~q);
            }
        }
    }
    __syncthreads();
    float hf = (float)ishape[1], wf = (float)ishape[2];
    u64 me = key[t];
    if (me) {
        int r = 0;
        for (int j = 0; j < 1024; ++j) r += (key[j] > me);
        if (r < TOPK) {
            int idx = (int)(~(unsigned)(me & 0xFFFFFFFFull));
            ordTop[r] = idx;
            topIdx[r] = idx;
            float bx1 = boxes[idx * 4 + 0], by1 = boxes[idx * 4 + 1];
            float bx2 = boxes[idx * 4 + 2], by2 = boxes[idx * 4 + 3];
            nfloat4 bp;
            bp.x = by1 / hf; bp.y = bx1 / wf;
            bp.z = (by2 - by1) / hf; bp.w = (bx2 - bx1) / wf;
            *(nfloat4*)(boxp + 4 * r) = bp;
        }
    }
    __syncthreads();
    for (int e = t; e < TOPK * (NCLS + 4); e += 1024) {
        int j = e / (NCLS + 4);
        int k2 = e - j * (NCLS + 4);
        int idx = ordTop[j];
        if (k2 < 4) out[OUT_B_OFF + j * 4 + k2] = boxes[(size_t)idx * 4 + k2];
        else        out[OUT_C_OFF + j * NCLS + (k2 - 4)] = cls[(size_t)idx * NCLS + (k2 - 4)];
    }
}

// ROI: 4 positions / block; 64 lanes/position, 4 channels/lane. bf16 feats.
// Phase-split: all 20 corner loads issued before any FMA/store (5x MLP).
template <int USE_BF16>
__global__ __launch_bounds__(256) void k_roi(
    const float* __restrict__ boxp, const int* __restrict__ topIdx,
    const ushort* __restrict__ feat,
    const float* __restrict__ f0, const float* __restrict__ f1,
    const float* __restrict__ f2, const float* __restrict__ f3,
    const float* __restrict__ f4,
    float* __restrict__ out) {
    const int lvlOff[5] = {0, 16384, 20480, 21504, 21760};
    int nwg = gridDim.x;
    int q = nwg >> 3, r = nwg & 7;
    int orig = blockIdx.x;
    int xcd = orig & 7, i8 = orig >> 3;
    int wg = (xcd < r ? xcd * (q + 1) : r * (q + 1) + (xcd - r) * q) + i8;
    int P  = wg * 4 + (threadIdx.x >> 6);
    int c4 = threadIdx.x & 63;
    int j = P / NPOS;
    int pos = P - j * NPOS;
    int y = pos / 14, x = pos - (pos / 14) * 14;
    nfloat4 bp = *(const nfloat4*)(boxp + 4 * j);
    float ty = (float)y / 13.0f;
    float tx = (float)x / 13.0f;
    const float* fm[5] = {f0, f1, f2, f3, f4};
    float* o = out + OUT_R_OFF + (size_t)P * (NLEV * 256);

    nfloat4 wgt[5];
    bool vld[5];
    ushort4 A[5], B[5], C[5], D[5];
    float4 FA[5], FB[5], FC[5], FD[5];
#pragma unroll
    for (int l = 0; l < NLEV; ++l) {
        int H = 128 >> l;
        float Hm1 = (float)(H - 1);
        float ys = (bp.x + ty * bp.z) * Hm1;
        float xs = (bp.y + tx * bp.w) * Hm1;
        float y0f = floorf(ys), x0f = floorf(xs);
        float wy = ys - y0f, wx = xs - x0f;
        int y0  = min(max((int)y0f, 0), H - 1);
        int y1c = min(max((int)y0f + 1, 0), H - 1);
        int x0  = min(max((int)x0f, 0), H - 1);
        int x1c = min(max((int)x0f + 1, 0), H - 1);
        vld[l] = (ys >= 0.0f) && (ys <= Hm1) && (xs >= 0.0f) && (xs <= Hm1);
        wgt[l].x = (1.0f - wy) * (1.0f - wx);
        wgt[l].y = (1.0f - wy) * wx;
        wgt[l].z = wy * (1.0f - wx);
        wgt[l].w = wy * wx;
        if (USE_BF16) {
            const ushort* base = feat + ((size_t)lvlOff[l] << 8);
            A[l] = ((const ushort4*)(base + ((size_t)(y0  * H + x0 ) << 8)))[c4];
            B[l] = ((const ushort4*)(base + ((size_t)(y0  * H + x1c) << 8)))[c4];
            C[l] = ((const ushort4*)(base + ((size_t)(y1c * H + x0 ) << 8)))[c4];
            D[l] = ((const ushort4*)(base + ((size_t)(y1c * H + x1c) << 8)))[c4];
        } else {
            const float* f = fm[l];
            FA[l] = ((const float4*)(f + ((size_t)(y0  * H + x0 ) << 8)))[c4];
            FB[l] = ((const float4*)(f + ((size_t)(y0  * H + x1c) << 8)))[c4];
            FC[l] = ((const float4*)(f + ((size_t)(y1c * H + x0 ) << 8)))[c4];
            FD[l] = ((const float4*)(f + ((size_t)(y1c * H + x1c) << 8)))[c4];
        }
    }
#pragma unroll
    for (int l = 0; l < NLEV; ++l) {
        float w00 = wgt[l].x, w01 = wgt[l].y, w10 = wgt[l].z, w11 = wgt[l].w;
        nfloat4 res;
        if (USE_BF16) {
#define BF(u) __uint_as_float(((unsigned)(u)) << 16)
            res.x = w00 * BF(A[l].x) + w01 * BF(B[l].x) + w10 * BF(C[l].x) + w11 * BF(D[l].x);
            res.y = w00 * BF(A[l].y) + w01 * BF(B[l].y) + w10 * BF(C[l].y) + w11 * BF(D[l].y);
            res.z = w00 * BF(A[l].z) + w01 * BF(B[l].z) + w10 * BF(C[l].z) + w11 * BF(D[l].z);
            res.w = w00 * BF(A[l].w) + w01 * BF(B[l].w) + w10 * BF(C[l].w) + w11 * BF(D[l].w);
#undef BF
        } else {
            res.x = w00 * FA[l].x + w01 * FB[l].x + w10 * FC[l].x + w11 * FD[l].x;
            res.y = w00 * FA[l].y + w01 * FB[l].y + w10 * FC[l].y + w11 * FD[l].y;
            res.z = w00 * FA[l].z + w01 * FB[l].z + w10 * FC[l].z + w11 * FD[l].z;
            res.w = w00 * FA[l].w + w01 * FB[l].w + w10 * FC[l].w + w11 * FD[l].w;
        }
        if (!vld[l]) { res.x = 0.f; res.y = 0.f; res.z = 0.f; res.w = 0.f; }
        __builtin_nontemporal_store(res, (nfloat4*)(o + l * 256) + c4);
    }
}

extern "C" void kernel_launch(void* const* d_in, const int* in_sizes, int n_in,
                              void* d_out, int out_size, void* d_ws, size_t ws_size,
                              hipStream_t stream) {
    const int*   ishape = (const int*)d_in[0];
    const float* boxes  = (const float*)d_in[1];
    const float* cls    = (const float*)d_in[2];
    const float* p3     = (const float*)d_in[3];
    const float* p4     = (const float*)d_in[4];
    const float* p5     = (const float*)d_in[5];
    const float* p6     = (const float*)d_in[6];
    const float* p7     = (const float*)d_in[7];
    float* out = (float*)d_out;

    int N = in_sizes[2] / NCLS;   // 196416

    char* ws = (char*)d_ws;
    int*    candCnt = (int*)(ws + WS_CNT);
    int*    topIdx  = (int*)(ws + WS_TOP);
    float*  boxp    = (float*)(ws + WS_BOXP);
    u64*    cand    = (u64*)(ws + WS_CAND);
    float*  scores  = (float*)(ws + WS_SCORES);
    ushort* feat    = (ushort*)(ws + WS_FEAT);

    bool useBf16 = ws_size >= (size_t)WS_FEAT + BF16_BYTES;

    hipLaunchKernelGGL(k_prep, dim3(SC_BLOCKS), dim3(256), 0, stream,
                       cls, scores, candCnt, cand, N);
    hipLaunchKernelGGL(k_topk, dim3(useBf16 ? 1 + CVT_BLOCKS : 1), dim3(1024), 0, stream,
                       scores, N, candCnt, cand, boxes, cls, ishape, topIdx, boxp, out,
                       p3, p4, p5, p6, p7, feat);
    if (useBf16)
        hipLaunchKernelGGL((k_roi<1>), dim3(TOPK * NPOS / 4), dim3(256), 0, stream,
                           boxp, topIdx, feat, p3, p4, p5, p6, p7, out);
    else
        hipLaunchKernelGGL((k_roi<0>), dim3(TOPK * NPOS / 4), dim3(256), 0, stream,
                           boxp, topIdx, feat, p3, p4, p5, p6, p7, out);
}